// Round 16
// baseline (348.901 us; speedup 1.0000x reference)
//
#include <hip/hip_runtime.h>
#include <hip/hip_bf16.h>
#include <math.h>

#define BB 4
#define NN 1024
#define KK 128
#define DD 32
#define LL 3
#define EH 130
#define EHP 132

typedef float f32x4 __attribute__((ext_vector_type(4)));
typedef short s16x8 __attribute__((ext_vector_type(8)));

__device__ __forceinline__ float lrelu(float x) { return fmaxf(x, 0.1f * x); }

__device__ __forceinline__ unsigned pk2(float a, float b) {   // v_cvt_pk_bf16_f32 (RNE)
    __hip_bfloat162 h = __float22bfloat162_rn(float2{a, b});
    return *(unsigned*)&h;
}
__device__ __forceinline__ unsigned short bf16_hu(float v) {
    return (unsigned short)((__float_as_uint(v) + 0x8000u) >> 16);
}
__device__ __forceinline__ unsigned short bf16_rne(float v) {
    unsigned u = __float_as_uint(v);
    return (unsigned short)((u + 0x7fffu + ((u >> 16) & 1u)) >> 16);
}

// ---- exact wave-level KNN select for one node (ballot binary search; R10-verified) ----
__device__ __forceinline__ void knn_select(const float2* __restrict__ cbp, int i, int lane,
                                           int* __restrict__ nb) {
    const float2 ci = cbp[i];
    unsigned k[16];
#pragma unroll
    for (int s = 0; s < 16; s++) {
        float2 cj = cbp[lane + 64 * s];
        float dx = ci.x - cj.x, dy = ci.y - cj.y;
        // match numpy per-op rounding exactly (no fma contraction)
        float d = __fadd_rn(__fmul_rn(dx, dx), __fmul_rn(dy, dy));
        k[s] = __float_as_uint(d);
    }
    // dstar = 128th smallest: MSB-first bitwise construction via ballot counts
    unsigned P = 0;
    for (int bpos = 30; bpos >= 0; bpos--) {
        const unsigned X = P | (1u << bpos);
        unsigned c = 0;
#pragma unroll
        for (int s = 0; s < 16; s++)
            c += (unsigned)__popcll(__ballot(k[s] < X));
        if (c < (unsigned)KK) P = X;
    }
    const unsigned dstar = P;
    const unsigned long long below = (1ull << lane) - 1ull;
    unsigned run = 0;
#pragma unroll
    for (int s = 0; s < 16; s++) {
        unsigned long long m = __ballot(k[s] < dstar);
        if (k[s] < dstar) nb[run + (unsigned)__popcll(m & below)] = lane + 64 * s;
        run += (unsigned)__popcll(m);
    }
    const int need = KK - (int)run;   // >= 1
    unsigned tie = 0;
    for (int s = 0; s < 16 && (int)tie < need; s++) {
        unsigned long long m = __ballot(k[s] == dstar);
        if (k[s] == dstar) {
            unsigned r = tie + (unsigned)__popcll(m & below);
            if ((int)r < need) nb[run + r] = lane + 64 * s;
        }
        tie += (unsigned)__popcll(m);
    }
}

// ---- prep: [0,2048) embed 2 nodes + layer-0 HI/HJ ; [2048,4096) knn-0 ; [4096,4192) frags ----
__global__ __launch_bounds__(128) void prep_kernel(
    const float* __restrict__ feat, const float* __restrict__ coor,
    const float* __restrict__ ew, const float* __restrict__ eb,
    float* __restrict__ fout,
    const float* __restrict__ e1w0, const float* __restrict__ e1b0,
    float* __restrict__ HI, float* __restrict__ HJ,
    int* __restrict__ nbr,
    const float* __restrict__ e2w, const float* __restrict__ c1w,
    unsigned short* __restrict__ e2f, unsigned short* __restrict__ c1f) {
    const int bid = blockIdx.x;
    const int t = threadIdx.x;
    if (bid < 2048) {
        // embed 2 nodes + their layer-0 HI/HJ (node-local)
        __shared__ float sfe[2][DD];
        const int n0 = bid * 2;
        if (t < 64) {
            const int nl = t >> 5, o = t & 31;
            const float* f = feat + (size_t)(n0 + nl) * DD;
            float a = eb[o];
#pragma unroll
            for (int k = 0; k < DD; k++) a = fmaf(f[k], ew[k * DD + o], a);
            a = lrelu(a);
            fout[(size_t)(n0 + nl) * DD + o] = a;
            sfe[nl][o] = a;
        }
        __syncthreads();
        for (int idx = t; idx < 2 * EHP; idx += 128) {
            const int nl = idx / EHP, o = idx - nl * EHP;
            const size_t off = (size_t)(n0 + nl) * EHP + o;
            if (o >= EH) { HI[off] = 0.f; HJ[off] = 0.f; continue; }
            const float* fl = sfe[nl];
            float aa = e1b0[o], cc = 0.f;
#pragma unroll
            for (int k = 0; k < DD; k++) aa = fmaf(fl[k], e1w0[k * EH + o], aa);
#pragma unroll
            for (int k = 0; k < DD; k++) cc = fmaf(fl[k], e1w0[(DD + k) * EH + o], cc);
            HI[off] = aa;
            HJ[off] = cc;
        }
    } else if (bid < 4096) {
        // knn for layer 0 on input coords: wave w handles node (bid-2048)*2 + w
        const int node = (bid - 2048) * 2 + (t >> 6);
        const int b = node >> 10, i = node & (NN - 1);
        knn_select((const float2*)coor + (size_t)b * NN, i, t & 63,
                   nbr + (size_t)node * KK);
    } else {
        // MFMA B-fragment precompute (bf16, fragment-ordered)
        for (int u = (bid - 4096) * 128 + t; u < 2 * LL * 4096; u += 96 * 128) {
            if (u < LL * 4096) {
                int jj = u & 7, la = (u >> 3) & 63, nt = (u >> 9) & 1, c = (u >> 10) & 3, l = u >> 12;
                int k = 32 * c + (la >> 4) * 8 + jj;
                int n = nt * 16 + (la & 15);
                e2f[u] = bf16_rne(e2w[(size_t)l * EH * DD + k * DD + n]);
            } else {
                int v = u - LL * 4096;
                int jj = v & 7, la = (v >> 3) & 63, nt = (v >> 9) & 7, l = v >> 12;
                int k = (la >> 4) * 8 + jj;
                int n = nt * 16 + (la & 15);
                c1f[v] = bf16_rne(c1w[(size_t)l * DD * 128 + k * 128 + n]);
            }
        }
    }
}

// ---- fused knn + HI/HJ precompute for layers 1,2 (R10-verified) ----
__global__ __launch_bounds__(256) void knnpre_kernel(
    const float* __restrict__ coors, int* __restrict__ nbr,
    const float* __restrict__ feats, const float* __restrict__ e1w, const float* __restrict__ e1b,
    float* __restrict__ HI, float* __restrict__ HJ) {
    const int KNNB = BB * NN / 4;
    if (blockIdx.x >= KNNB) {
        int t = (int)(blockIdx.x - KNNB) * 256 + threadIdx.x;
        if (t >= BB * NN * EHP) return;
        int n = t / EHP, o = t % EHP;
        if (o >= EH) { HI[t] = 0.f; HJ[t] = 0.f; return; }
        const float* f = feats + n * DD;
        float a = e1b[o], c = 0.f;
#pragma unroll
        for (int k = 0; k < DD; k++) a = fmaf(f[k], e1w[k * EH + o], a);
#pragma unroll
        for (int k = 0; k < DD; k++) c = fmaf(f[k], e1w[(DD + k) * EH + o], c);
        HI[t] = a;
        HJ[t] = c;
        return;
    }
    const int node = (int)blockIdx.x * 4 + (threadIdx.x >> 6);
    const int b = node >> 10, i = node & (NN - 1);
    knn_select((const float2*)coors + (size_t)b * NN, i, threadIdx.x & 63,
               nbr + (size_t)node * KK);
}

// ---- fused layer: R15 body + aggressive software pipelining of all global loads ----
__global__ __launch_bounds__(128) void layer_kernel(
    const float* __restrict__ feats_in, const float* __restrict__ coors_in,
    const int*   __restrict__ nbr,
    const float* __restrict__ HI, const float* __restrict__ HJ,
    const float* __restrict__ w65,
    const float* __restrict__ e2w,
    const float* __restrict__ e2b,
    const unsigned short* __restrict__ e2f,
    const unsigned short* __restrict__ c1f,
    const float* __restrict__ gw, const float* __restrict__ gb,
    const float* __restrict__ c1b, const float* __restrict__ c2w, const float* __restrict__ c2b,
    const float* __restrict__ n1w, const float* __restrict__ n1b,
    const float* __restrict__ n2w, const float* __restrict__ n2b,
    const float* __restrict__ scale,
    float* __restrict__ feats_out, float* __restrict__ coors_out) {
    const int node = blockIdx.x;
    const int b = node >> 10;
    const int t = threadIdx.x;
    const int lane = t & 63, wid = t >> 6;
    const int ln = lane & 15, q = lane >> 4;
    const int rowbase = wid * 64;

    __shared__ __align__(16) float shi[EHP];
    __shared__ __align__(16) float sw65[EHP];
    __shared__ __align__(16) unsigned short smA[2 * 64 * 32];
    __shared__ float sx0[128], sx1[128], su[128], sv[128];
    __shared__ float sgw[DD], se2b[DD], sfi[DD];
    __shared__ float sc1b[128], sc2w[128];
    __shared__ float redm[2][DD], redc[2][2];
    __shared__ float sni[2 * DD], shd[2 * DD];

    for (int u = t; u < EHP; u += 128) {
        shi[u] = HI[(size_t)node * EHP + u];
        sw65[u] = (u < EH) ? w65[u] : 0.f;
    }
    if (t < DD) { sfi[t] = feats_in[node * DD + t]; sgw[t] = gw[t]; se2b[t] = e2b[t]; }
    sc1b[t] = c1b[t];
    sc2w[t] = c2w[t];
    __syncthreads();

    const float cix = coors_in[node * 2], ciy = coors_in[node * 2 + 1];
    const int j = nbr[(size_t)node * KK + t];
    const float2 cj = *(const float2*)(coors_in + ((size_t)(b * NN) + j) * 2);
    const float dx = cix - cj.x, dy = ciy - cj.y;
    const float rd = __fadd_rn(__fmul_rn(dx, dx), __fmul_rn(dy, dy));
    const float nrm = fmaxf(sqrtf(rd), 1e-8f);
    const float s = scale[0] / nrm;
    su[t] = dx * s;
    sv[t] = dy * s;

    // rows this lane consumes as A-fragments: wave-private -> __shfl
    const float* hjb[4];
    float rdR[4];
#pragma unroll
    for (int mt = 0; mt < 4; mt++) {
        int jR = __shfl(j, mt * 16 + ln, 64);
        rdR[mt] = __shfl(rd, mt * 16 + ln, 64);
        hjb[mt] = HJ + ((size_t)(b * NN) + jR) * EHP;
    }

    // ---- early issue: chunk-0 HJ frags, chunk-0 e2 B-frags, epilogue e2w rows ----
    float4 ha[4], hbv[4];
#pragma unroll
    for (int mt = 0; mt < 4; mt++) {
        const float4* hjp = (const float4*)(hjb[mt] + q * 8);
        ha[mt] = hjp[0];
        hbv[mt] = hjp[1];
    }
    s16x8 b0 = *(const s16x8*)(e2f + (0 * 64 + lane) * 8);
    s16x8 b1 = *(const s16x8*)(e2f + (1 * 64 + lane) * 8);
    float w128a, w129a, w128b, w129b;
    {
        w128a = e2w[128 * DD + ln];
        w129a = e2w[129 * DD + ln];
        w128b = e2w[128 * DD + 16 + ln];
        w129b = e2w[129 * DD + 16 + ln];
    }

    {   // h1 features k=128,129 kept exact fp32 (VALU tail in the e2 epilogue)
        const float2 hjt = *(const float2*)(HJ + ((size_t)(b * NN) + j) * EHP + 128);
        sx0[t] = lrelu(shi[128] + hjt.x + rd * sw65[128]);
        sx1[t] = lrelu(shi[129] + hjt.y + rd * sw65[129]);
    }

    const float4* shi4 = (const float4*)shi;
    const float4* sw4  = (const float4*)sw65;

    const f32x4 zz = {0.f, 0.f, 0.f, 0.f};
    f32x4 accA[4][2];
#pragma unroll
    for (int mt = 0; mt < 4; mt++) { accA[mt][0] = zz; accA[mt][1] = zz; }

#pragma unroll 1
    for (int c = 0; c < 4; c++) {
        // prefetch next chunk's B-frags and HJ frags (depth-1 pipeline)
        s16x8 nb0, nb1;
        float4 nha[4], nhb[4];
        if (c < 3) {
            nb0 = *(const s16x8*)(e2f + (((c + 1) * 2 + 0) * 64 + lane) * 8);
            nb1 = *(const s16x8*)(e2f + (((c + 1) * 2 + 1) * 64 + lane) * 8);
#pragma unroll
            for (int mt = 0; mt < 4; mt++) {
                const float4* hjp = (const float4*)(hjb[mt] + (c + 1) * 32 + q * 8);
                nha[mt] = hjp[0];
                nhb[mt] = hjp[1];
            }
        }
        const int kb = c * 8 + q * 2;
        const float4 hi0 = shi4[kb], hi1 = shi4[kb + 1];
        const float4 wv0 = sw4[kb],  wv1 = sw4[kb + 1];
#pragma unroll
        for (int mt = 0; mt < 4; mt++) {
            const float r = rdR[mt];
            union { s16x8 v; unsigned u[4]; } A;
            A.u[0] = pk2(lrelu(hi0.x + ha[mt].x + r * wv0.x), lrelu(hi0.y + ha[mt].y + r * wv0.y));
            A.u[1] = pk2(lrelu(hi0.z + ha[mt].z + r * wv0.z), lrelu(hi0.w + ha[mt].w + r * wv0.w));
            A.u[2] = pk2(lrelu(hi1.x + hbv[mt].x + r * wv1.x), lrelu(hi1.y + hbv[mt].y + r * wv1.y));
            A.u[3] = pk2(lrelu(hi1.z + hbv[mt].z + r * wv1.z), lrelu(hi1.w + hbv[mt].w + r * wv1.w));
            accA[mt][0] = __builtin_amdgcn_mfma_f32_16x16x32_bf16(A.v, b0, accA[mt][0], 0, 0, 0);
            accA[mt][1] = __builtin_amdgcn_mfma_f32_16x16x32_bf16(A.v, b1, accA[mt][1], 0, 0, 0);
        }
        b0 = nb0;
        b1 = nb1;
#pragma unroll
        for (int mt = 0; mt < 4; mt++) { ha[mt] = nha[mt]; hbv[mt] = nhb[mt]; }
    }

    // ---- prefetch first c1 B-frags (independent of what follows)
    s16x8 bc0 = *(const s16x8*)(c1f + (0 * 64 + lane) * 8);
    s16x8 bc1 = *(const s16x8*)(c1f + (1 * 64 + lane) * 8);

    // ---- e2 epilogue: bias + exact k=128,129 tail + lrelu (C layout)
#pragma unroll
    for (int nt = 0; nt < 2; nt++) {
        const int col = nt * 16 + ln;
        const float w128 = nt ? w128b : w128a;
        const float w129 = nt ? w129b : w129a;
        const float bv = se2b[col];
#pragma unroll
        for (int mt = 0; mt < 4; mt++)
#pragma unroll
            for (int r = 0; r < 4; r++) {
                const int row = rowbase + mt * 16 + q * 4 + r;
                accA[mt][nt][r] = lrelu(accA[mt][nt][r] + bv + sx0[row] * w128 + sx1[row] * w129);
            }
    }

    const float gbv = gb[0];
#pragma unroll
    for (int mt = 0; mt < 4; mt++) {
        float p[4];
#pragma unroll
        for (int r = 0; r < 4; r++)
            p[r] = accA[mt][0][r] * sgw[ln] + accA[mt][1][r] * sgw[16 + ln];
#pragma unroll
        for (int off = 1; off <= 8; off <<= 1)
#pragma unroll
            for (int r = 0; r < 4; r++) p[r] += __shfl_xor(p[r], off);
#pragma unroll
        for (int r = 0; r < 4; r++) {
            const float g = 1.f / (1.f + __expf(-(p[r] + gbv)));
            accA[mt][0][r] *= g;
            accA[mt][1][r] *= g;
        }
    }

    float mi0 = 0.f, mi1 = 0.f;
#pragma unroll
    for (int mt = 0; mt < 4; mt++)
#pragma unroll
        for (int r = 0; r < 4; r++) { mi0 += accA[mt][0][r]; mi1 += accA[mt][1][r]; }
    mi0 += __shfl_xor(mi0, 16); mi0 += __shfl_xor(mi0, 32);
    mi1 += __shfl_xor(mi1, 16); mi1 += __shfl_xor(mi1, 32);
    if (lane < 16) { redm[wid][lane] = mi0; redm[wid][16 + lane] = mi1; }

    unsigned short* smw = smA + wid * (64 * 32);
#pragma unroll
    for (int mt = 0; mt < 4; mt++)
#pragma unroll
        for (int nt = 0; nt < 2; nt++)
#pragma unroll
            for (int r = 0; r < 4; r++) {
                const int prow = (r << 4) | (4 * mt + q);
                smw[prow * 32 + nt * 16 + ln] = bf16_hu(accA[mt][nt][r]);
            }

    s16x8 a4[4];
#pragma unroll
    for (int mt = 0; mt < 4; mt++) {
        const int prow = ((ln & 3) << 4) | (4 * mt + (ln >> 2));
        a4[mt] = *(const s16x8*)(smw + prow * 32 + q * 8);
    }

    float cacc[4][4];
#pragma unroll
    for (int mt = 0; mt < 4; mt++)
#pragma unroll
        for (int r = 0; r < 4; r++) cacc[mt][r] = 0.f;

#pragma unroll 1
    for (int g = 0; g < 4; g++) {
        s16x8 nbc0, nbc1;
        if (g < 3) {   // depth-1 prefetch of next g's B-frags
            nbc0 = *(const s16x8*)(c1f + ((2 * (g + 1) + 0) * 64 + lane) * 8);
            nbc1 = *(const s16x8*)(c1f + ((2 * (g + 1) + 1) * 64 + lane) * 8);
        }
        f32x4 c20[4], c21[4];
#pragma unroll
        for (int mt = 0; mt < 4; mt++) {
            c20[mt] = __builtin_amdgcn_mfma_f32_16x16x32_bf16(a4[mt], bc0, zz, 0, 0, 0);
            c21[mt] = __builtin_amdgcn_mfma_f32_16x16x32_bf16(a4[mt], bc1, zz, 0, 0, 0);
        }
#pragma unroll
        for (int h = 0; h < 2; h++) {
            const int col = (2 * g + h) * 16 + ln;
            const float c1bv = sc1b[col], c2wv = sc2w[col];
#pragma unroll
            for (int mt = 0; mt < 4; mt++)
#pragma unroll
                for (int r = 0; r < 4; r++) {
                    const float v = (h ? c21[mt][r] : c20[mt][r]) + c1bv;
                    cacc[mt][r] = fmaf(lrelu(v), c2wv, cacc[mt][r]);
                }
        }
        bc0 = nbc0;
        bc1 = nbc1;
    }
#pragma unroll
    for (int off = 1; off <= 8; off <<= 1)
#pragma unroll
        for (int mt = 0; mt < 4; mt++)
#pragma unroll
            for (int r = 0; r < 4; r++) cacc[mt][r] += __shfl_xor(cacc[mt][r], off);

    const float c2bv = c2b[0];
    float vxp = 0.f, vyp = 0.f;
    if (ln == 0) {
#pragma unroll
        for (int mt = 0; mt < 4; mt++)
#pragma unroll
            for (int r = 0; r < 4; r++) {
                const int row = rowbase + mt * 16 + q * 4 + r;
                const float cw = cacc[mt][r] + c2bv;
                vxp = fmaf(cw, su[row], vxp);
                vyp = fmaf(cw, sv[row], vyp);
            }
    }
    vxp += __shfl_xor(vxp, 16); vxp += __shfl_xor(vxp, 32);
    vyp += __shfl_xor(vyp, 16); vyp += __shfl_xor(vyp, 32);
    if (lane == 0) { redc[wid][0] = vxp; redc[wid][1] = vyp; }

    __syncthreads();
    if (t < DD) {
        sni[t] = sfi[t];
        sni[DD + t] = redm[0][t] + redm[1][t];
    }
    __syncthreads();
    if (t < 2 * DD) {
        float a = n1b[t];
#pragma unroll
        for (int k = 0; k < 2 * DD; k++) a = fmaf(sni[k], n1w[k * 2 * DD + t], a);
        shd[t] = lrelu(a);
    }
    __syncthreads();
    if (t < DD) {
        float a = n2b[t];
#pragma unroll
        for (int o = 0; o < 2 * DD; o++) a = fmaf(shd[o], n2w[o * DD + t], a);
        feats_out[node * DD + t] = a + sfi[t];
    }
    if (t == 0) {
        coors_out[node * 2] = cix + redc[0][0] + redc[1][0];
        coors_out[node * 2 + 1] = ciy + redc[0][1] + redc[1][1];
    }
}

extern "C" void kernel_launch(void* const* d_in, const int* in_sizes, int n_in,
                              void* d_out, int out_size, void* d_ws, size_t ws_size,
                              hipStream_t stream) {
    const float* feat_   = (const float*)d_in[0];
    const float* coor_   = (const float*)d_in[1];
    // d_in[2] = batch (int32, unused: equal-size graphs)
    const float* embed_w = (const float*)d_in[3];
    const float* embed_b = (const float*)d_in[4];
    const float* e1_w    = (const float*)d_in[5];
    const float* e1_b    = (const float*)d_in[6];
    const float* e2_w    = (const float*)d_in[7];
    const float* e2_b    = (const float*)d_in[8];
    const float* gate_w  = (const float*)d_in[9];
    const float* gate_b  = (const float*)d_in[10];
    const float* c1_w    = (const float*)d_in[11];
    const float* c1_b    = (const float*)d_in[12];
    const float* c2_w    = (const float*)d_in[13];
    const float* c2_b    = (const float*)d_in[14];
    const float* n1_w    = (const float*)d_in[15];
    const float* n1_b    = (const float*)d_in[16];
    const float* n2_w    = (const float*)d_in[17];
    const float* n2_b    = (const float*)d_in[18];
    const float* cscale  = (const float*)d_in[19];

    float* ws = (float*)d_ws;
    float* fa   = ws;   ws += BB * NN * DD;
    float* fb   = ws;   ws += BB * NN * DD;
    float* ca   = ws;   ws += BB * NN * 2;
    float* cb2  = ws;   ws += BB * NN * 2;
    float* HIa  = ws;   ws += BB * NN * EHP;
    float* HJa  = ws;   ws += BB * NN * EHP;
    unsigned short* e2f = (unsigned short*)ws;      // LL*4096 ushorts
    unsigned short* c1f = e2f + LL * 4096;          // LL*4096 ushorts
    int* nbr = (int*)(c1f + LL * 4096);

    // launch 1: embed + layer-0 HI/HJ + knn-0 + B-frags (all node-local / independent)
    prep_kernel<<<4096 + 96, 128, 0, stream>>>(feat_, coor_, embed_w, embed_b, fa,
                                               e1_w, e1_b, HIa, HJa, nbr,
                                               e2_w, c1_w, e2f, c1f);

    const int KNNB = BB * NN / 4;
    const int PREB = (BB * NN * EHP + 255) / 256;
    const float* fin = fa;
    const float* cin = coor_;
    float* fouts[LL] = {fb, fa, (float*)d_out};
    float* couts[LL] = {ca, cb2, ca};

    for (int l = 0; l < LL; l++) {
        if (l > 0)   // knn + HI/HJ pre for this layer, on previous layer's outputs
            knnpre_kernel<<<KNNB + PREB, 256, 0, stream>>>(
                cin, nbr, fin, e1_w + (size_t)l * 65 * EH, e1_b + (size_t)l * EH, HIa, HJa);
        layer_kernel<<<BB * NN, 128, 0, stream>>>(
            fin, cin, nbr, HIa, HJa,
            e1_w + ((size_t)l * 65 + 64) * EH,
            e2_w + (size_t)l * EH * DD,
            e2_b + (size_t)l * DD,
            e2f + (size_t)l * 4096,
            c1f + (size_t)l * 4096,
            gate_w + (size_t)l * DD,
            gate_b + l,
            c1_b + (size_t)l * 128,
            c2_w + (size_t)l * 128,
            c2_b + l,
            n1_w + (size_t)l * 64 * 64,
            n1_b + (size_t)l * 64,
            n2_w + (size_t)l * 64 * 32,
            n2_b + (size_t)l * DD,
            cscale + l,
            fouts[l], couts[l]);
        fin = fouts[l];
        cin = couts[l];
    }
}

// Round 17
// 322.834 us; speedup vs baseline: 1.0807x; 1.0807x over previous
//
#include <hip/hip_runtime.h>
#include <hip/hip_bf16.h>
#include <math.h>

#define BB 4
#define NN 1024
#define KK 128
#define DD 32
#define LL 3
#define EH 130
#define EHP 132

typedef float f32x4 __attribute__((ext_vector_type(4)));
typedef short s16x8 __attribute__((ext_vector_type(8)));

__device__ __forceinline__ float lrelu(float x) { return fmaxf(x, 0.1f * x); }

__device__ __forceinline__ unsigned pk2(float a, float b) {   // v_cvt_pk_bf16_f32 (RNE)
    __hip_bfloat162 h = __float22bfloat162_rn(float2{a, b});
    return *(unsigned*)&h;
}
__device__ __forceinline__ unsigned short bf16_hu(float v) {
    return (unsigned short)((__float_as_uint(v) + 0x8000u) >> 16);
}
__device__ __forceinline__ unsigned short bf16_rne(float v) {
    unsigned u = __float_as_uint(v);
    return (unsigned short)((u + 0x7fffu + ((u >> 16) & 1u)) >> 16);
}

// ---- exact wave-level KNN select for one node (ballot binary search; R10-verified) ----
__device__ __forceinline__ void knn_select(const float2* __restrict__ cbp, int i, int lane,
                                           int* __restrict__ nb) {
    const float2 ci = cbp[i];
    unsigned k[16];
#pragma unroll
    for (int s = 0; s < 16; s++) {
        float2 cj = cbp[lane + 64 * s];
        float dx = ci.x - cj.x, dy = ci.y - cj.y;
        // match numpy per-op rounding exactly (no fma contraction)
        float d = __fadd_rn(__fmul_rn(dx, dx), __fmul_rn(dy, dy));
        k[s] = __float_as_uint(d);
    }
    // dstar = 128th smallest: MSB-first bitwise construction via ballot counts
    unsigned P = 0;
    for (int bpos = 30; bpos >= 0; bpos--) {
        const unsigned X = P | (1u << bpos);
        unsigned c = 0;
#pragma unroll
        for (int s = 0; s < 16; s++)
            c += (unsigned)__popcll(__ballot(k[s] < X));
        if (c < (unsigned)KK) P = X;
    }
    const unsigned dstar = P;
    const unsigned long long below = (1ull << lane) - 1ull;
    unsigned run = 0;
#pragma unroll
    for (int s = 0; s < 16; s++) {
        unsigned long long m = __ballot(k[s] < dstar);
        if (k[s] < dstar) nb[run + (unsigned)__popcll(m & below)] = lane + 64 * s;
        run += (unsigned)__popcll(m);
    }
    const int need = KK - (int)run;   // >= 1
    unsigned tie = 0;
    for (int s = 0; s < 16 && (int)tie < need; s++) {
        unsigned long long m = __ballot(k[s] == dstar);
        if (k[s] == dstar) {
            unsigned r = tie + (unsigned)__popcll(m & below);
            if ((int)r < need) nb[run + r] = lane + 64 * s;
        }
        tie += (unsigned)__popcll(m);
    }
}

// ---- prep: [0,2048) embed 2 nodes + layer-0 HI/HJ ; [2048,4096) knn-0 ; [4096,4192) frags ----
__global__ __launch_bounds__(128) void prep_kernel(
    const float* __restrict__ feat, const float* __restrict__ coor,
    const float* __restrict__ ew, const float* __restrict__ eb,
    float* __restrict__ fout,
    const float* __restrict__ e1w0, const float* __restrict__ e1b0,
    float* __restrict__ HI, float* __restrict__ HJ,
    int* __restrict__ nbr,
    const float* __restrict__ e2w, const float* __restrict__ c1w,
    unsigned short* __restrict__ e2f, unsigned short* __restrict__ c1f) {
    const int bid = blockIdx.x;
    const int t = threadIdx.x;
    if (bid < 2048) {
        // embed 2 nodes + their layer-0 HI/HJ (node-local)
        __shared__ float sfe[2][DD];
        const int n0 = bid * 2;
        if (t < 64) {
            const int nl = t >> 5, o = t & 31;
            const float* f = feat + (size_t)(n0 + nl) * DD;
            float a = eb[o];
#pragma unroll
            for (int k = 0; k < DD; k++) a = fmaf(f[k], ew[k * DD + o], a);
            a = lrelu(a);
            fout[(size_t)(n0 + nl) * DD + o] = a;
            sfe[nl][o] = a;
        }
        __syncthreads();
        for (int idx = t; idx < 2 * EHP; idx += 128) {
            const int nl = idx / EHP, o = idx - nl * EHP;
            const size_t off = (size_t)(n0 + nl) * EHP + o;
            if (o >= EH) { HI[off] = 0.f; HJ[off] = 0.f; continue; }
            const float* fl = sfe[nl];
            float aa = e1b0[o], cc = 0.f;
#pragma unroll
            for (int k = 0; k < DD; k++) aa = fmaf(fl[k], e1w0[k * EH + o], aa);
#pragma unroll
            for (int k = 0; k < DD; k++) cc = fmaf(fl[k], e1w0[(DD + k) * EH + o], cc);
            HI[off] = aa;
            HJ[off] = cc;
        }
    } else if (bid < 4096) {
        // knn for layer 0 on input coords: wave w handles node (bid-2048)*2 + w
        const int node = (bid - 2048) * 2 + (t >> 6);
        const int b = node >> 10, i = node & (NN - 1);
        knn_select((const float2*)coor + (size_t)b * NN, i, t & 63,
                   nbr + (size_t)node * KK);
    } else {
        // MFMA B-fragment precompute (bf16, fragment-ordered)
        for (int u = (bid - 4096) * 128 + t; u < 2 * LL * 4096; u += 96 * 128) {
            if (u < LL * 4096) {
                int jj = u & 7, la = (u >> 3) & 63, nt = (u >> 9) & 1, c = (u >> 10) & 3, l = u >> 12;
                int k = 32 * c + (la >> 4) * 8 + jj;
                int n = nt * 16 + (la & 15);
                e2f[u] = bf16_rne(e2w[(size_t)l * EH * DD + k * DD + n]);
            } else {
                int v = u - LL * 4096;
                int jj = v & 7, la = (v >> 3) & 63, nt = (v >> 9) & 7, l = v >> 12;
                int k = (la >> 4) * 8 + jj;
                int n = nt * 16 + (la & 15);
                c1f[v] = bf16_rne(c1w[(size_t)l * DD * 128 + k * 128 + n]);
            }
        }
    }
}

// ---- fused knn + HI/HJ precompute for layers 1,2 (R10-verified) ----
__global__ __launch_bounds__(256) void knnpre_kernel(
    const float* __restrict__ coors, int* __restrict__ nbr,
    const float* __restrict__ feats, const float* __restrict__ e1w, const float* __restrict__ e1b,
    float* __restrict__ HI, float* __restrict__ HJ) {
    const int KNNB = BB * NN / 4;
    if (blockIdx.x >= KNNB) {
        int t = (int)(blockIdx.x - KNNB) * 256 + threadIdx.x;
        if (t >= BB * NN * EHP) return;
        int n = t / EHP, o = t % EHP;
        if (o >= EH) { HI[t] = 0.f; HJ[t] = 0.f; return; }
        const float* f = feats + n * DD;
        float a = e1b[o], c = 0.f;
#pragma unroll
        for (int k = 0; k < DD; k++) a = fmaf(f[k], e1w[k * EH + o], a);
#pragma unroll
        for (int k = 0; k < DD; k++) c = fmaf(f[k], e1w[(DD + k) * EH + o], c);
        HI[t] = a;
        HJ[t] = c;
        return;
    }
    const int node = (int)blockIdx.x * 4 + (threadIdx.x >> 6);
    const int b = node >> 10, i = node & (NN - 1);
    knn_select((const float2*)coors + (size_t)b * NN, i, threadIdx.x & 63,
               nbr + (size_t)node * KK);
}

// ---- fused layer: MFMA e2 + gate + MFMA c1 + reductions + node MLP (R15 body, verified) ----
__global__ __launch_bounds__(128) void layer_kernel(
    const float* __restrict__ feats_in, const float* __restrict__ coors_in,
    const int*   __restrict__ nbr,
    const float* __restrict__ HI, const float* __restrict__ HJ,
    const float* __restrict__ w65,
    const float* __restrict__ e2w,
    const float* __restrict__ e2b,
    const unsigned short* __restrict__ e2f,
    const unsigned short* __restrict__ c1f,
    const float* __restrict__ gw, const float* __restrict__ gb,
    const float* __restrict__ c1b, const float* __restrict__ c2w, const float* __restrict__ c2b,
    const float* __restrict__ n1w, const float* __restrict__ n1b,
    const float* __restrict__ n2w, const float* __restrict__ n2b,
    const float* __restrict__ scale,
    float* __restrict__ feats_out, float* __restrict__ coors_out) {
    const int node = blockIdx.x;
    const int b = node >> 10;
    const int t = threadIdx.x;
    const int lane = t & 63, wid = t >> 6;
    const int ln = lane & 15, q = lane >> 4;
    const int rowbase = wid * 64;

    __shared__ __align__(16) float shi[EHP];
    __shared__ __align__(16) float sw65[EHP];
    __shared__ __align__(16) unsigned short smA[2 * 64 * 32];
    __shared__ float sx0[128], sx1[128], su[128], sv[128];
    __shared__ float sgw[DD], se2b[DD], sfi[DD];
    __shared__ float sc1b[128], sc2w[128];
    __shared__ float redm[2][DD], redc[2][2];
    __shared__ float sni[2 * DD], shd[2 * DD];

    for (int u = t; u < EHP; u += 128) {
        shi[u] = HI[(size_t)node * EHP + u];
        sw65[u] = (u < EH) ? w65[u] : 0.f;
    }
    if (t < DD) { sfi[t] = feats_in[node * DD + t]; sgw[t] = gw[t]; se2b[t] = e2b[t]; }
    sc1b[t] = c1b[t];
    sc2w[t] = c2w[t];
    __syncthreads();

    const float cix = coors_in[node * 2], ciy = coors_in[node * 2 + 1];
    const int j = nbr[(size_t)node * KK + t];
    const float2 cj = *(const float2*)(coors_in + ((size_t)(b * NN) + j) * 2);
    const float dx = cix - cj.x, dy = ciy - cj.y;
    const float rd = __fadd_rn(__fmul_rn(dx, dx), __fmul_rn(dy, dy));
    const float nrm = fmaxf(sqrtf(rd), 1e-8f);
    const float s = scale[0] / nrm;
    su[t] = dx * s;
    sv[t] = dy * s;

    {
        const float2 hjt = *(const float2*)(HJ + ((size_t)(b * NN) + j) * EHP + 128);
        sx0[t] = lrelu(shi[128] + hjt.x + rd * sw65[128]);
        sx1[t] = lrelu(shi[129] + hjt.y + rd * sw65[129]);
    }

    const float* hjb[4];
    float rdR[4];
#pragma unroll
    for (int mt = 0; mt < 4; mt++) {
        int jR = __shfl(j, mt * 16 + ln, 64);
        rdR[mt] = __shfl(rd, mt * 16 + ln, 64);
        hjb[mt] = HJ + ((size_t)(b * NN) + jR) * EHP;
    }

    const float4* shi4 = (const float4*)shi;
    const float4* sw4  = (const float4*)sw65;

    const f32x4 zz = {0.f, 0.f, 0.f, 0.f};
    f32x4 accA[4][2];
#pragma unroll
    for (int mt = 0; mt < 4; mt++) { accA[mt][0] = zz; accA[mt][1] = zz; }

    float4 ha[4], hbv[4];
#pragma unroll
    for (int mt = 0; mt < 4; mt++) {
        const float4* hjp = (const float4*)(hjb[mt] + q * 8);
        ha[mt] = hjp[0];
        hbv[mt] = hjp[1];
    }

#pragma unroll 1
    for (int c = 0; c < 4; c++) {
        s16x8 b0 = *(const s16x8*)(e2f + ((c * 2 + 0) * 64 + lane) * 8);
        s16x8 b1 = *(const s16x8*)(e2f + ((c * 2 + 1) * 64 + lane) * 8);
        float4 nha[4], nhb[4];
        if (c < 3) {
#pragma unroll
            for (int mt = 0; mt < 4; mt++) {
                const float4* hjp = (const float4*)(hjb[mt] + (c + 1) * 32 + q * 8);
                nha[mt] = hjp[0];
                nhb[mt] = hjp[1];
            }
        }
        const int kb = c * 8 + q * 2;
        const float4 hi0 = shi4[kb], hi1 = shi4[kb + 1];
        const float4 wv0 = sw4[kb],  wv1 = sw4[kb + 1];
#pragma unroll
        for (int mt = 0; mt < 4; mt++) {
            const float r = rdR[mt];
            union { s16x8 v; unsigned u[4]; } A;
            A.u[0] = pk2(lrelu(hi0.x + ha[mt].x + r * wv0.x), lrelu(hi0.y + ha[mt].y + r * wv0.y));
            A.u[1] = pk2(lrelu(hi0.z + ha[mt].z + r * wv0.z), lrelu(hi0.w + ha[mt].w + r * wv0.w));
            A.u[2] = pk2(lrelu(hi1.x + hbv[mt].x + r * wv1.x), lrelu(hi1.y + hbv[mt].y + r * wv1.y));
            A.u[3] = pk2(lrelu(hi1.z + hbv[mt].z + r * wv1.z), lrelu(hi1.w + hbv[mt].w + r * wv1.w));
            accA[mt][0] = __builtin_amdgcn_mfma_f32_16x16x32_bf16(A.v, b0, accA[mt][0], 0, 0, 0);
            accA[mt][1] = __builtin_amdgcn_mfma_f32_16x16x32_bf16(A.v, b1, accA[mt][1], 0, 0, 0);
        }
#pragma unroll
        for (int mt = 0; mt < 4; mt++) { ha[mt] = nha[mt]; hbv[mt] = nhb[mt]; }
    }

#pragma unroll
    for (int nt = 0; nt < 2; nt++) {
        const int col = nt * 16 + ln;
        const float w128 = e2w[128 * DD + col];
        const float w129 = e2w[129 * DD + col];
        const float bv = se2b[col];
#pragma unroll
        for (int mt = 0; mt < 4; mt++)
#pragma unroll
            for (int r = 0; r < 4; r++) {
                const int row = rowbase + mt * 16 + q * 4 + r;
                accA[mt][nt][r] = lrelu(accA[mt][nt][r] + bv + sx0[row] * w128 + sx1[row] * w129);
            }
    }

    const float gbv = gb[0];
#pragma unroll
    for (int mt = 0; mt < 4; mt++) {
        float p[4];
#pragma unroll
        for (int r = 0; r < 4; r++)
            p[r] = accA[mt][0][r] * sgw[ln] + accA[mt][1][r] * sgw[16 + ln];
#pragma unroll
        for (int off = 1; off <= 8; off <<= 1)
#pragma unroll
            for (int r = 0; r < 4; r++) p[r] += __shfl_xor(p[r], off);
#pragma unroll
        for (int r = 0; r < 4; r++) {
            const float g = 1.f / (1.f + __expf(-(p[r] + gbv)));
            accA[mt][0][r] *= g;
            accA[mt][1][r] *= g;
        }
    }

    float mi0 = 0.f, mi1 = 0.f;
#pragma unroll
    for (int mt = 0; mt < 4; mt++)
#pragma unroll
        for (int r = 0; r < 4; r++) { mi0 += accA[mt][0][r]; mi1 += accA[mt][1][r]; }
    mi0 += __shfl_xor(mi0, 16); mi0 += __shfl_xor(mi0, 32);
    mi1 += __shfl_xor(mi1, 16); mi1 += __shfl_xor(mi1, 32);
    if (lane < 16) { redm[wid][lane] = mi0; redm[wid][16 + lane] = mi1; }

    unsigned short* smw = smA + wid * (64 * 32);
#pragma unroll
    for (int mt = 0; mt < 4; mt++)
#pragma unroll
        for (int nt = 0; nt < 2; nt++)
#pragma unroll
            for (int r = 0; r < 4; r++) {
                const int prow = (r << 4) | (4 * mt + q);
                smw[prow * 32 + nt * 16 + ln] = bf16_hu(accA[mt][nt][r]);
            }

    s16x8 a4[4];
#pragma unroll
    for (int mt = 0; mt < 4; mt++) {
        const int prow = ((ln & 3) << 4) | (4 * mt + (ln >> 2));
        a4[mt] = *(const s16x8*)(smw + prow * 32 + q * 8);
    }

    float cacc[4][4];
#pragma unroll
    for (int mt = 0; mt < 4; mt++)
#pragma unroll
        for (int r = 0; r < 4; r++) cacc[mt][r] = 0.f;

#pragma unroll 1
    for (int g = 0; g < 4; g++) {
        s16x8 bc0 = *(const s16x8*)(c1f + ((2 * g + 0) * 64 + lane) * 8);
        s16x8 bc1 = *(const s16x8*)(c1f + ((2 * g + 1) * 64 + lane) * 8);
        f32x4 c20[4], c21[4];
#pragma unroll
        for (int mt = 0; mt < 4; mt++) {
            c20[mt] = __builtin_amdgcn_mfma_f32_16x16x32_bf16(a4[mt], bc0, zz, 0, 0, 0);
            c21[mt] = __builtin_amdgcn_mfma_f32_16x16x32_bf16(a4[mt], bc1, zz, 0, 0, 0);
        }
#pragma unroll
        for (int h = 0; h < 2; h++) {
            const int col = (2 * g + h) * 16 + ln;
            const float c1bv = sc1b[col], c2wv = sc2w[col];
#pragma unroll
            for (int mt = 0; mt < 4; mt++)
#pragma unroll
                for (int r = 0; r < 4; r++) {
                    const float v = (h ? c21[mt][r] : c20[mt][r]) + c1bv;
                    cacc[mt][r] = fmaf(lrelu(v), c2wv, cacc[mt][r]);
                }
        }
    }
#pragma unroll
    for (int off = 1; off <= 8; off <<= 1)
#pragma unroll
        for (int mt = 0; mt < 4; mt++)
#pragma unroll
            for (int r = 0; r < 4; r++) cacc[mt][r] += __shfl_xor(cacc[mt][r], off);

    const float c2bv = c2b[0];
    float vxp = 0.f, vyp = 0.f;
    if (ln == 0) {
#pragma unroll
        for (int mt = 0; mt < 4; mt++)
#pragma unroll
            for (int r = 0; r < 4; r++) {
                const int row = rowbase + mt * 16 + q * 4 + r;
                const float cw = cacc[mt][r] + c2bv;
                vxp = fmaf(cw, su[row], vxp);
                vyp = fmaf(cw, sv[row], vyp);
            }
    }
    vxp += __shfl_xor(vxp, 16); vxp += __shfl_xor(vxp, 32);
    vyp += __shfl_xor(vyp, 16); vyp += __shfl_xor(vyp, 32);
    if (lane == 0) { redc[wid][0] = vxp; redc[wid][1] = vyp; }

    __syncthreads();
    if (t < DD) {
        sni[t] = sfi[t];
        sni[DD + t] = redm[0][t] + redm[1][t];
    }
    __syncthreads();
    if (t < 2 * DD) {
        float a = n1b[t];
#pragma unroll
        for (int k = 0; k < 2 * DD; k++) a = fmaf(sni[k], n1w[k * 2 * DD + t], a);
        shd[t] = lrelu(a);
    }
    __syncthreads();
    if (t < DD) {
        float a = n2b[t];
#pragma unroll
        for (int o = 0; o < 2 * DD; o++) a = fmaf(shd[o], n2w[o * DD + t], a);
        feats_out[node * DD + t] = a + sfi[t];
    }
    if (t == 0) {
        coors_out[node * 2] = cix + redc[0][0] + redc[1][0];
        coors_out[node * 2 + 1] = ciy + redc[0][1] + redc[1][1];
    }
}

extern "C" void kernel_launch(void* const* d_in, const int* in_sizes, int n_in,
                              void* d_out, int out_size, void* d_ws, size_t ws_size,
                              hipStream_t stream) {
    const float* feat_   = (const float*)d_in[0];
    const float* coor_   = (const float*)d_in[1];
    // d_in[2] = batch (int32, unused: equal-size graphs)
    const float* embed_w = (const float*)d_in[3];
    const float* embed_b = (const float*)d_in[4];
    const float* e1_w    = (const float*)d_in[5];
    const float* e1_b    = (const float*)d_in[6];
    const float* e2_w    = (const float*)d_in[7];
    const float* e2_b    = (const float*)d_in[8];
    const float* gate_w  = (const float*)d_in[9];
    const float* gate_b  = (const float*)d_in[10];
    const float* c1_w    = (const float*)d_in[11];
    const float* c1_b    = (const float*)d_in[12];
    const float* c2_w    = (const float*)d_in[13];
    const float* c2_b    = (const float*)d_in[14];
    const float* n1_w    = (const float*)d_in[15];
    const float* n1_b    = (const float*)d_in[16];
    const float* n2_w    = (const float*)d_in[17];
    const float* n2_b    = (const float*)d_in[18];
    const float* cscale  = (const float*)d_in[19];

    float* ws = (float*)d_ws;
    float* fa   = ws;   ws += BB * NN * DD;
    float* fb   = ws;   ws += BB * NN * DD;
    float* ca   = ws;   ws += BB * NN * 2;
    float* cb2  = ws;   ws += BB * NN * 2;
    float* HIa  = ws;   ws += BB * NN * EHP;
    float* HJa  = ws;   ws += BB * NN * EHP;
    unsigned short* e2f = (unsigned short*)ws;      // LL*4096 ushorts
    unsigned short* c1f = e2f + LL * 4096;          // LL*4096 ushorts
    int* nbr = (int*)(c1f + LL * 4096);

    // launch 1: embed + layer-0 HI/HJ + knn-0 + B-frags (all node-local / independent)
    prep_kernel<<<4096 + 96, 128, 0, stream>>>(feat_, coor_, embed_w, embed_b, fa,
                                               e1_w, e1_b, HIa, HJa, nbr,
                                               e2_w, c1_w, e2f, c1f);

    const int KNNB = BB * NN / 4;
    const int PREB = (BB * NN * EHP + 255) / 256;
    const float* fin = fa;
    const float* cin = coor_;
    float* fouts[LL] = {fb, fa, (float*)d_out};
    float* couts[LL] = {ca, cb2, ca};

    for (int l = 0; l < LL; l++) {
        if (l > 0)   // knn + HI/HJ pre for this layer, on previous layer's outputs
            knnpre_kernel<<<KNNB + PREB, 256, 0, stream>>>(
                cin, nbr, fin, e1_w + (size_t)l * 65 * EH, e1_b + (size_t)l * EH, HIa, HJa);
        layer_kernel<<<BB * NN, 128, 0, stream>>>(
            fin, cin, nbr, HIa, HJa,
            e1_w + ((size_t)l * 65 + 64) * EH,
            e2_w + (size_t)l * EH * DD,
            e2_b + (size_t)l * DD,
            e2f + (size_t)l * 4096,
            c1f + (size_t)l * 4096,
            gate_w + (size_t)l * DD,
            gate_b + l,
            c1_b + (size_t)l * 128,
            c2_w + (size_t)l * 128,
            c2_b + l,
            n1_w + (size_t)l * 64 * 64,
            n1_b + (size_t)l * 64,
            n2_w + (size_t)l * 64 * 32,
            n2_b + (size_t)l * DD,
            cscale + l,
            fouts[l], couts[l]);
        fin = fouts[l];
        cin = couts[l];
    }
}